// Round 1
// baseline (274.267 us; speedup 1.0000x reference)
//
#include <hip/hip_runtime.h>
#include <cmath>

// K[n,m] = sv^2 * sum_p (x1[n,p]-off)*(x2[m,p]-off) + sb^2
// N = M = 8192, P = 16. Output fp32 256 MB -> write-BW-bound (~47 us floor).
//
// 128x128 tile per 256-thread block. LDS holds (x - off) tiles TRANSPOSED
// ([p][row], stride 132 = 128+4 pad) so compute reads are ds_read_b128 with
// lane-contiguous addresses (2-way bank alias = free). Each thread: split
// 8x8 register tile (rows {ty*4..+3, 64+ty*4..+3} x cols {tx*4..+3, 64+tx*4..+3}).

#define TILE 128
#define LDST 132   // padded row stride (floats) for transposed LDS tiles

__global__ __launch_bounds__(256) void linear_kernel(
    const float* __restrict__ x1, const float* __restrict__ x2,
    const float* __restrict__ p_lsb, const float* __restrict__ p_lsv,
    const float* __restrict__ p_off, float* __restrict__ out, int ldout)
{
    __shared__ float s1[16 * LDST];  // s1[p*LDST + row] = x1[n0+row][p] - off
    __shared__ float s2[16 * LDST];  // s2[p*LDST + row] = x2[m0+row][p] - off

    const int tid = threadIdx.x;
    const int tx = tid & 15;         // column group
    const int ty = tid >> 4;         // row group
    const int n0 = blockIdx.y * TILE;
    const int m0 = blockIdx.x * TILE;

    const float off = p_off[0];
    const float sb  = expf(p_lsb[0]);
    const float sv  = expf(p_lsv[0]);
    const float sv2 = sv * sv;
    const float sb2 = sb * sb;

    // ---- Stage global -> LDS (transposed, offset-subtracted) ----
    // Tile of x1: rows n0..n0+127, 16 floats each = 512 float4, contiguous.
    const float4* g1 = (const float4*)(x1 + (size_t)n0 * 16);
    const float4* g2 = (const float4*)(x2 + (size_t)m0 * 16);
    #pragma unroll
    for (int j = tid; j < 512; j += 256) {
        const int row = j >> 2;
        const int p0  = (j & 3) * 4;
        float4 v = g1[j];
        s1[(p0 + 0) * LDST + row] = v.x - off;
        s1[(p0 + 1) * LDST + row] = v.y - off;
        s1[(p0 + 2) * LDST + row] = v.z - off;
        s1[(p0 + 3) * LDST + row] = v.w - off;
        float4 w = g2[j];
        s2[(p0 + 0) * LDST + row] = w.x - off;
        s2[(p0 + 1) * LDST + row] = w.y - off;
        s2[(p0 + 2) * LDST + row] = w.z - off;
        s2[(p0 + 3) * LDST + row] = w.w - off;
    }

    float acc[8][8];
    #pragma unroll
    for (int r = 0; r < 8; ++r)
        #pragma unroll
        for (int c = 0; c < 8; ++c) acc[r][c] = 0.0f;

    __syncthreads();

    // ---- Rank-16 outer-product accumulation ----
    #pragma unroll
    for (int p = 0; p < 16; ++p) {
        const float* s1p = &s1[p * LDST];
        const float* s2p = &s2[p * LDST];
        const float4 a0 = *(const float4*)&s1p[ty * 4];        // rows ty*4..+3
        const float4 a1 = *(const float4*)&s1p[64 + ty * 4];   // rows 64+ty*4..+3
        const float4 b0 = *(const float4*)&s2p[tx * 4];        // cols tx*4..+3
        const float4 b1 = *(const float4*)&s2p[64 + tx * 4];   // cols 64+tx*4..+3
        const float av[8] = {a0.x, a0.y, a0.z, a0.w, a1.x, a1.y, a1.z, a1.w};
        const float bv[8] = {b0.x, b0.y, b0.z, b0.w, b1.x, b1.y, b1.z, b1.w};
        #pragma unroll
        for (int r = 0; r < 8; ++r)
            #pragma unroll
            for (int c = 0; c < 8; ++c)
                acc[r][c] += av[r] * bv[c];
    }

    // ---- Epilogue: K = sv2*acc + sb2, vectorized float4 stores ----
    #pragma unroll
    for (int r = 0; r < 8; ++r) {
        const int lr  = (r < 4) ? (ty * 4 + r) : (64 + ty * 4 + (r - 4));
        float* orow = out + (size_t)(n0 + lr) * (size_t)ldout + m0;
        float4 o0, o1;
        o0.x = sv2 * acc[r][0] + sb2;
        o0.y = sv2 * acc[r][1] + sb2;
        o0.z = sv2 * acc[r][2] + sb2;
        o0.w = sv2 * acc[r][3] + sb2;
        o1.x = sv2 * acc[r][4] + sb2;
        o1.y = sv2 * acc[r][5] + sb2;
        o1.z = sv2 * acc[r][6] + sb2;
        o1.w = sv2 * acc[r][7] + sb2;
        *(float4*)&orow[tx * 4]      = o0;
        *(float4*)&orow[64 + tx * 4] = o1;
    }
}

extern "C" void kernel_launch(void* const* d_in, const int* in_sizes, int n_in,
                              void* d_out, int out_size, void* d_ws, size_t ws_size,
                              hipStream_t stream) {
    const float* x1  = (const float*)d_in[0];
    const float* x2  = (const float*)d_in[1];
    const float* lsb = (const float*)d_in[2];
    const float* lsv = (const float*)d_in[3];
    const float* off = (const float*)d_in[4];
    float* out = (float*)d_out;

    const int n = in_sizes[0] / 16;   // 8192
    const int m = in_sizes[1] / 16;   // 8192

    dim3 grid(m / TILE, n / TILE);    // 64 x 64 blocks
    linear_kernel<<<grid, 256, 0, stream>>>(x1, x2, lsb, lsv, off, out, m);
}